// Round 5
// baseline (213.317 us; speedup 1.0000x reference)
//
#include <hip/hip_runtime.h>

typedef __bf16 bf16x8 __attribute__((ext_vector_type(8)));
typedef float floatx4 __attribute__((ext_vector_type(4)));

// split fp32 -> bf16 hi + bf16 lo (x ~= hi + lo, residual ~2^-17)
__device__ inline void cvt8_hl(const float* __restrict__ p, bf16x8& h, bf16x8& l){
  float4 v0 = *reinterpret_cast<const float4*>(p);
  float4 v1 = *reinterpret_cast<const float4*>(p + 4);
  float v[8] = {v0.x, v0.y, v0.z, v0.w, v1.x, v1.y, v1.z, v1.w};
  #pragma unroll
  for (int i = 0; i < 8; ++i) {
    __bf16 hi = (__bf16)v[i];
    h[i] = hi;
    l[i] = (__bf16)(v[i] - (float)hi);
  }
}

// ---------------------------------------------------------------------------
// K1 (round-0 proven, byte-identical; ~31us). ILP > TLP for this skinny GEMM
// (R1/R3 post-mortem). Do not touch.
// ---------------------------------------------------------------------------
__global__ __launch_bounds__(256) void k1_gemm(
    const float* __restrict__ x,
    const float* __restrict__ Wt,
    const float* __restrict__ Wg,
    float* __restrict__ mod)
{
  __shared__ float red[3][32][64];   // waves 1..3 partials, 24 KB
  const int tid  = threadIdx.x;
  const int wave = tid >> 6, lane = tid & 63;
  const int quad = lane >> 4, r16 = lane & 15;
  const int ff = blockIdx.x * 16 + r16;
  const int kb = wave * 256 + quad * 8;

  floatx4 accT[4], accG[4];
  #pragma unroll
  for (int m = 0; m < 4; ++m) { accT[m] = (floatx4)0.0f; accG[m] = (floatx4)0.0f; }

  const float* wt = Wt + ff * 1024 + kb;
  const float* wg = Wg + ff * 1024 + kb;
  const float* xp = x  + r16 * 1024 + kb;

  #pragma unroll
  for (int it = 0; it < 8; ++it) {
    const int ko = it * 32;
    bf16x8 bth, btl, bgh, bgl;
    cvt8_hl(wt + ko, bth, btl);
    cvt8_hl(wg + ko, bgh, bgl);
    #pragma unroll
    for (int mt = 0; mt < 4; ++mt) {
      bf16x8 ah, al;
      cvt8_hl(xp + mt * 16384 + ko, ah, al);
      accT[mt] = __builtin_amdgcn_mfma_f32_16x16x32_bf16(ah, bth, accT[mt], 0, 0, 0);
      accT[mt] = __builtin_amdgcn_mfma_f32_16x16x32_bf16(ah, btl, accT[mt], 0, 0, 0);
      accT[mt] = __builtin_amdgcn_mfma_f32_16x16x32_bf16(al, bth, accT[mt], 0, 0, 0);
      accG[mt] = __builtin_amdgcn_mfma_f32_16x16x32_bf16(ah, bgh, accG[mt], 0, 0, 0);
      accG[mt] = __builtin_amdgcn_mfma_f32_16x16x32_bf16(ah, bgl, accG[mt], 0, 0, 0);
      accG[mt] = __builtin_amdgcn_mfma_f32_16x16x32_bf16(al, bgh, accG[mt], 0, 0, 0);
    }
  }

  if (wave != 0) {
    #pragma unroll
    for (int mt = 0; mt < 4; ++mt)
      #pragma unroll
      for (int r = 0; r < 4; ++r) {
        red[wave - 1][mt * 4 + r][lane]      = accT[mt][r];
        red[wave - 1][16 + mt * 4 + r][lane] = accG[mt][r];
      }
  }
  __syncthreads();
  if (wave == 0) {
    #pragma unroll
    for (int mt = 0; mt < 4; ++mt) {
      #pragma unroll
      for (int r = 0; r < 4; ++r) {
        float t = accT[mt][r] + red[0][mt * 4 + r][lane]
                              + red[1][mt * 4 + r][lane]
                              + red[2][mt * 4 + r][lane];
        float g = accG[mt][r] + red[0][16 + mt * 4 + r][lane]
                              + red[1][16 + mt * 4 + r][lane]
                              + red[2][16 + mt * 4 + r][lane];
        float sig = 1.0f / (1.0f + __expf(-g));
        int b = mt * 16 + quad * 4 + r;          // C/D: row = quad*4 + reg
        mod[b * 8192 + ff] = t * g * sig;
      }
    }
  }
}

// ---------------------------------------------------------------------------
// K1b (round-0 proven): s[b*4+k] = rsqrt(mean(|mod[b,k,:]|) + eps)
// ---------------------------------------------------------------------------
__global__ __launch_bounds__(256) void k1b_scale(const float* __restrict__ mod,
                                                 float* __restrict__ s)
{
  const int row = blockIdx.x;
  const int tid = threadIdx.x;
  const float* p = mod + row * 2048;
  float sum = 0.0f;
  #pragma unroll
  for (int q = 0; q < 8; ++q) sum += fabsf(p[q * 256 + tid]);
  #pragma unroll
  for (int o = 1; o < 64; o <<= 1) sum += __shfl_xor(sum, o, 64);
  __shared__ float ls[4];
  if ((tid & 63) == 0) ls[tid >> 6] = sum;
  __syncthreads();
  if (tid == 0) {
    float t = ls[0] + ls[1] + ls[2] + ls[3];
    s[row] = rsqrtf(t * (1.0f / 2048.0f) + 1e-4f);
  }
}

// ---------------------------------------------------------------------------
// K2 v2 (b-inner restructure): grid (32,8) = 256 blocks; block owns a fixed
// 8i x 32j patch; weights (wm0/wm1/A1) in REGISTERS, read once; loop all 64
// b's in groups of 8 with a/bp vectors staged in LDS. Per-b wave shfl-reduce
// of mag -> LDS bsum[b] -> one atomicAdd per b per block into partial[b].
// R1-R4 evidence: k2+k4 ~115us invariant to 4x grid => not occupancy; this
// attacks weight re-read (64x -> 1x) + gives 64-deep per-thread b-loop ILP.
// ---------------------------------------------------------------------------
__global__ __launch_bounds__(256) void k2_mag(
    const float* __restrict__ mod, const float* __restrict__ s,
    const float* __restrict__ wstat,
    const float* __restrict__ wmod,
    const float* __restrict__ cw,
    const float* __restrict__ cb,
    float* __restrict__ partial)     // partial[64]: per-b mag sums
{
  const int ibase = blockIdx.x * 8, jbase = blockIdx.y * 32;
  const int tid = threadIdx.x;
  const int il = tid >> 5, jl = tid & 31;
  const int i = ibase + il, j = jbase + jl;
  const int ij = i * 256 + j;

  __shared__ float a_l[8][8][8];      // [bb][i][kr] 2 KB (broadcast reads)
  __shared__ float bp_l[8][32][12];   // [bb][j][kr] pad->12, 12 KB (4-way max)
  __shared__ float sk_l[256];
  __shared__ float bsum[64];

  float weff[4]; float beff = 0.0f;
  #pragma unroll
  for (int r = 0; r < 4; ++r) {
    weff[r] = cw[r] + cw[4 + r] + cw[8 + r] + cw[12 + r];
    beff += cb[r];
  }
  sk_l[tid] = s[tid];
  if (tid < 64) bsum[tid] = 0.0f;
  const float wm0 = wmod[ij];
  const float wm1 = wmod[65536 + ij];
  const float2 A1 = *reinterpret_cast<const float2*>(wstat + 131072 + ij * 2);
  __syncthreads();

  for (int g = 0; g < 8; ++g) {
    const int b0 = g * 8;
    // stage a: 8b x 8i x 8kr = 512 (2 passes, lanes->consecutive i)
    #pragma unroll
    for (int q = 0; q < 2; ++q) {
      int ee = q * 256 + tid;
      int bb = ee >> 6, kr = (ee >> 3) & 7, i2 = ee & 7;
      int b = b0 + bb, k = kr >> 2, r = kr & 3;
      a_l[bb][i2][kr] = mod[b * 8192 + k * 2048 + r * 512 + ibase + i2]
                        * (sk_l[b * 4 + k] * weff[r]);
    }
    // stage bp: 8b x 8kr x 32j (coalesced over j)
    {
      int kr = tid >> 5, k = kr >> 2, r = kr & 3;
      #pragma unroll
      for (int bb = 0; bb < 8; ++bb) {
        int b = b0 + bb;
        bp_l[bb][jl][kr] = mod[b * 8192 + k * 2048 + r * 512 + 256 + j]
                           * sk_l[b * 4 + k];
      }
    }
    __syncthreads();
    #pragma unroll
    for (int bb = 0; bb < 8; ++bb) {
      const float* ap  = a_l[bb][il];
      const float* bpp = bp_l[bb][jl];
      float d0 = ap[0]*bpp[0] + ap[1]*bpp[1] + ap[2]*bpp[2] + ap[3]*bpp[3];
      float d1 = ap[4]*bpp[4] + ap[5]*bpp[5] + ap[6]*bpp[6] + ap[7]*bpp[7];
      float m0 = wm0 * (d0 + beff);
      float m1 = wm1 * (d1 + beff);
      float re = A1.x * m0 - A1.y * m1;
      float im = A1.x * m1 - A1.y * m0;
      float mg = sqrtf(re * re + im * im + 1e-4f);
      #pragma unroll
      for (int o = 1; o < 64; o <<= 1) mg += __shfl_xor(mg, o, 64);
      if ((tid & 63) == 0) atomicAdd(&bsum[b0 + bb], mg);
    }
    __syncthreads();
  }
  if (tid < 64) atomicAdd(&partial[tid], bsum[tid]);
}

// ---------------------------------------------------------------------------
// K4 v2 (b-inner restructure): same patch scheme as K2 v2; weights (wm0..3,
// A0, A1) in registers once; 64 b's in 8 groups of 8, a/bp staged in LDS
// (bp padded to 20 floats: 16B-aligned float4 reads, 4-way conflicts max).
// Coalesced scalar stores (32 consecutive j per wave-half).
// ---------------------------------------------------------------------------
__global__ __launch_bounds__(256) void k4_out(
    const float* __restrict__ mod, const float* __restrict__ s,
    const float* __restrict__ wstat,
    const float* __restrict__ wmod,
    const float* __restrict__ cw,
    const float* __restrict__ cb,
    const float* __restrict__ partial,
    float* __restrict__ out)
{
  const int ibase = blockIdx.x * 8, jbase = blockIdx.y * 32;
  const int tid = threadIdx.x;
  const int il = tid >> 5, jl = tid & 31;
  const int i = ibase + il, j = jbase + jl;
  const int ij = i * 256 + j;

  __shared__ __align__(16) float a_l[8][8][16];    // [bb][i][kr] 4 KB
  __shared__ __align__(16) float bp_l[8][32][20];  // [bb][j][kr] pad->20, 20 KB
  __shared__ float sk_l[256];
  __shared__ float inv_l[64];

  float weff[4]; float beff = 0.0f;
  #pragma unroll
  for (int r = 0; r < 4; ++r) {
    weff[r] = cw[r] + cw[4 + r] + cw[8 + r] + cw[12 + r];
    beff += cb[r];
  }
  sk_l[tid] = s[tid];
  if (tid < 64) inv_l[tid] = rsqrtf(partial[tid] * (1.0f / 65536.0f) + 1e-4f);
  const float wm0 = wmod[ij];
  const float wm1 = wmod[65536  + ij];
  const float wm2 = wmod[131072 + ij];
  const float wm3 = wmod[196608 + ij];
  const float2 A0 = *reinterpret_cast<const float2*>(wstat + ij * 2);
  const float2 A1 = *reinterpret_cast<const float2*>(wstat + 131072 + ij * 2);
  __syncthreads();

  for (int g = 0; g < 8; ++g) {
    const int b0 = g * 8;
    // stage a: 8b x 8i x 16kr = 1024 (4 passes, lanes->consecutive i)
    #pragma unroll
    for (int q = 0; q < 4; ++q) {
      int ee = q * 256 + tid;
      int bb = ee >> 7, kr = (ee >> 3) & 15, i2 = ee & 7;
      int b = b0 + bb, k = kr >> 2, r = kr & 3;
      a_l[bb][i2][kr] = mod[b * 8192 + k * 2048 + r * 512 + ibase + i2]
                        * (sk_l[b * 4 + k] * weff[r]);
    }
    // stage bp: 8b x 16kr x 32j (coalesced over j)
    {
      int kr0 = tid >> 5;
      #pragma unroll
      for (int bb = 0; bb < 8; ++bb) {
        int b = b0 + bb;
        #pragma unroll
        for (int h = 0; h < 2; ++h) {
          int kr = kr0 + h * 8, k = kr >> 2, r = kr & 3;
          bp_l[bb][jl][kr] = mod[b * 8192 + k * 2048 + r * 512 + 256 + j]
                             * sk_l[b * 4 + k];
        }
      }
    }
    __syncthreads();
    #pragma unroll
    for (int bb = 0; bb < 8; ++bb) {
      const int b = b0 + bb;
      const float4 a0 = *reinterpret_cast<const float4*>(&a_l[bb][il][0]);
      const float4 a1 = *reinterpret_cast<const float4*>(&a_l[bb][il][4]);
      const float4 a2 = *reinterpret_cast<const float4*>(&a_l[bb][il][8]);
      const float4 a3 = *reinterpret_cast<const float4*>(&a_l[bb][il][12]);
      const float4 b0v = *reinterpret_cast<const float4*>(&bp_l[bb][jl][0]);
      const float4 b1v = *reinterpret_cast<const float4*>(&bp_l[bb][jl][4]);
      const float4 b2v = *reinterpret_cast<const float4*>(&bp_l[bb][jl][8]);
      const float4 b3v = *reinterpret_cast<const float4*>(&bp_l[bb][jl][12]);
      float d0 = a0.x*b0v.x + a0.y*b0v.y + a0.z*b0v.z + a0.w*b0v.w;
      float d1 = a1.x*b1v.x + a1.y*b1v.y + a1.z*b1v.z + a1.w*b1v.w;
      float d2 = a2.x*b2v.x + a2.y*b2v.y + a2.z*b2v.z + a2.w*b2v.w;
      float d3 = a3.x*b3v.x + a3.y*b3v.y + a3.z*b3v.z + a3.w*b3v.w;
      float m0 = wm0 * (d0 + beff);
      float m1 = wm1 * (d1 + beff);
      float m2 = wm2 * (d2 + beff);
      float m3 = wm3 * (d3 + beff);
      float re = A1.x * m0 - A1.y * m1;
      float im = A1.x * m1 - A1.y * m0;
      float inv = inv_l[b];
      float mwre = A0.x + re * inv;
      float mwim = A0.y + im * inv;
      float rd = rsqrtf(m2 * m2 + m3 * m3 + 1e-4f);
      out[b * 65536 + ij] = (mwre * m2 + mwim * m3) * rd;
    }
    __syncthreads();
  }
}

extern "C" void kernel_launch(void* const* d_in, const int* in_sizes, int n_in,
                              void* d_out, int out_size, void* d_ws, size_t ws_size,
                              hipStream_t stream) {
  const float* x     = (const float*)d_in[0];
  const float* Wt    = (const float*)d_in[1];
  const float* Wg    = (const float*)d_in[2];
  const float* wstat = (const float*)d_in[3];
  const float* wmod  = (const float*)d_in[4];
  const float* cw    = (const float*)d_in[5];
  const float* cb    = (const float*)d_in[6];

  float* mod     = (float*)d_ws;           // 524288 floats
  float* sbuf    = mod + 524288;           // 256 floats (rsqrt scales)
  float* partial = sbuf + 256;             // 64 floats (per-b mag sums)

  hipMemsetAsync(partial, 0, 64 * sizeof(float), stream);
  k1_gemm  <<<512, 256, 0, stream>>>(x, Wt, Wg, mod);
  k1b_scale<<<256, 256, 0, stream>>>(mod, sbuf);
  k2_mag   <<<dim3(32, 8), 256, 0, stream>>>(mod, sbuf, wstat, wmod, cw, cb, partial);
  k4_out   <<<dim3(32, 8), 256, 0, stream>>>(mod, sbuf, wstat, wmod, cw, cb, partial,
                                             (float*)d_out);
}

// Round 7
// 162.236 us; speedup vs baseline: 1.3149x; 1.3149x over previous
//
#include <hip/hip_runtime.h>

typedef __bf16 bf16x8 __attribute__((ext_vector_type(8)));
typedef float floatx4 __attribute__((ext_vector_type(4)));

// split fp32 -> bf16 hi + bf16 lo (x ~= hi + lo, residual ~2^-17)
__device__ inline void cvt8_hl(const float* __restrict__ p, bf16x8& h, bf16x8& l){
  float4 v0 = *reinterpret_cast<const float4*>(p);
  float4 v1 = *reinterpret_cast<const float4*>(p + 4);
  float v[8] = {v0.x, v0.y, v0.z, v0.w, v1.x, v1.y, v1.z, v1.w};
  #pragma unroll
  for (int i = 0; i < 8; ++i) {
    __bf16 hi = (__bf16)v[i];
    h[i] = hi;
    l[i] = (__bf16)(v[i] - (float)hi);
  }
}

// ---------------------------------------------------------------------------
// K1 (round-0 proven, byte-identical; ~31us). ILP > TLP for this workload
// (R1/R3/R5 post-mortems). Do not touch.
// ---------------------------------------------------------------------------
__global__ __launch_bounds__(256) void k1_gemm(
    const float* __restrict__ x,
    const float* __restrict__ Wt,
    const float* __restrict__ Wg,
    float* __restrict__ mod)
{
  __shared__ float red[3][32][64];   // waves 1..3 partials, 24 KB
  const int tid  = threadIdx.x;
  const int wave = tid >> 6, lane = tid & 63;
  const int quad = lane >> 4, r16 = lane & 15;
  const int ff = blockIdx.x * 16 + r16;
  const int kb = wave * 256 + quad * 8;

  floatx4 accT[4], accG[4];
  #pragma unroll
  for (int m = 0; m < 4; ++m) { accT[m] = (floatx4)0.0f; accG[m] = (floatx4)0.0f; }

  const float* wt = Wt + ff * 1024 + kb;
  const float* wg = Wg + ff * 1024 + kb;
  const float* xp = x  + r16 * 1024 + kb;

  #pragma unroll
  for (int it = 0; it < 8; ++it) {
    const int ko = it * 32;
    bf16x8 bth, btl, bgh, bgl;
    cvt8_hl(wt + ko, bth, btl);
    cvt8_hl(wg + ko, bgh, bgl);
    #pragma unroll
    for (int mt = 0; mt < 4; ++mt) {
      bf16x8 ah, al;
      cvt8_hl(xp + mt * 16384 + ko, ah, al);
      accT[mt] = __builtin_amdgcn_mfma_f32_16x16x32_bf16(ah, bth, accT[mt], 0, 0, 0);
      accT[mt] = __builtin_amdgcn_mfma_f32_16x16x32_bf16(ah, btl, accT[mt], 0, 0, 0);
      accT[mt] = __builtin_amdgcn_mfma_f32_16x16x32_bf16(al, bth, accT[mt], 0, 0, 0);
      accG[mt] = __builtin_amdgcn_mfma_f32_16x16x32_bf16(ah, bgh, accG[mt], 0, 0, 0);
      accG[mt] = __builtin_amdgcn_mfma_f32_16x16x32_bf16(ah, bgl, accG[mt], 0, 0, 0);
      accG[mt] = __builtin_amdgcn_mfma_f32_16x16x32_bf16(al, bgh, accG[mt], 0, 0, 0);
    }
  }

  if (wave != 0) {
    #pragma unroll
    for (int mt = 0; mt < 4; ++mt)
      #pragma unroll
      for (int r = 0; r < 4; ++r) {
        red[wave - 1][mt * 4 + r][lane]      = accT[mt][r];
        red[wave - 1][16 + mt * 4 + r][lane] = accG[mt][r];
      }
  }
  __syncthreads();
  if (wave == 0) {
    #pragma unroll
    for (int mt = 0; mt < 4; ++mt) {
      #pragma unroll
      for (int r = 0; r < 4; ++r) {
        float t = accT[mt][r] + red[0][mt * 4 + r][lane]
                              + red[1][mt * 4 + r][lane]
                              + red[2][mt * 4 + r][lane];
        float g = accG[mt][r] + red[0][16 + mt * 4 + r][lane]
                              + red[1][16 + mt * 4 + r][lane]
                              + red[2][16 + mt * 4 + r][lane];
        float sig = 1.0f / (1.0f + __expf(-g));
        int b = mt * 16 + quad * 4 + r;          // C/D: row = quad*4 + reg
        mod[b * 8192 + ff] = t * g * sig;
      }
    }
  }
}

// ---------------------------------------------------------------------------
// K1b (round-0 proven): s[b*4+k] = rsqrt(mean(|mod[b,k,:]|) + eps)
// ---------------------------------------------------------------------------
__global__ __launch_bounds__(256) void k1b_scale(const float* __restrict__ mod,
                                                 float* __restrict__ s)
{
  const int row = blockIdx.x;
  const int tid = threadIdx.x;
  const float* p = mod + row * 2048;
  float sum = 0.0f;
  #pragma unroll
  for (int q = 0; q < 8; ++q) sum += fabsf(p[q * 256 + tid]);
  #pragma unroll
  for (int o = 1; o < 64; o <<= 1) sum += __shfl_xor(sum, o, 64);
  __shared__ float ls[4];
  if ((tid & 63) == 0) ls[tid >> 6] = sum;
  __syncthreads();
  if (tid == 0) {
    float t = ls[0] + ls[1] + ls[2] + ls[3];
    s[row] = rsqrtf(t * (1.0f / 2048.0f) + 1e-4f);
  }
}

// ---------------------------------------------------------------------------
// K2 v3: grid (32,8,4) = 1024 blocks (4-5/CU). Block = 8i x 32j patch x 16 b.
// ALL global loads (weights->regs, a/bp of all 16 b -> LDS) issued as one
// independent ~20-load/thread batch before the single __syncthreads (k1
// recipe: outstanding-miss depth is the currency post-poison). Compute is
// pure LDS/VALU, 16-deep b-loop. LDS bp stride 13 (coprime 32, conflict-
// free scalar reads). Per-b: 64-lane shfl reduce -> LDS bsum -> global atomic.
// ---------------------------------------------------------------------------
__global__ __launch_bounds__(256) void k2_mag(
    const float* __restrict__ mod, const float* __restrict__ s,
    const float* __restrict__ wstat,
    const float* __restrict__ wmod,
    const float* __restrict__ cw,
    const float* __restrict__ cb,
    float* __restrict__ partial)     // partial[64]: per-b mag sums
{
  const int ibase = blockIdx.x * 8, jbase = blockIdx.y * 32, bbase = blockIdx.z * 16;
  const int tid = threadIdx.x;
  const int il = tid >> 5, jl = tid & 31;
  const int i = ibase + il, j = jbase + jl;
  const int ij = i * 256 + j;

  __shared__ float a_l[16][8][8];     // 4 KB (broadcast reads)
  __shared__ float bp_l[16][32][13];  // 26 KB, stride 13 -> conflict-free
  __shared__ float bsum[16];

  // weights for this thread's (i,j): independent loads, issue first
  const float wm0 = wmod[ij];
  const float wm1 = wmod[65536 + ij];
  const float2 A1 = *reinterpret_cast<const float2*>(wstat + 131072 + ij * 2);

  float weff[4]; float beff = 0.0f;
  #pragma unroll
  for (int r = 0; r < 4; ++r) {
    weff[r] = cw[r] + cw[4 + r] + cw[8 + r] + cw[12 + r];
    beff += cb[r];
  }
  if (tid < 16) bsum[tid] = 0.0f;

  // stage a: 16b x 8i x 8kr = 1024 (4 passes; s[] is L2-hot from k1b)
  #pragma unroll
  for (int q = 0; q < 4; ++q) {
    int ee = q * 256 + tid;
    int bb = ee >> 6, kr = (ee >> 3) & 7, i2 = ee & 7;
    int b = bbase + bb, k = kr >> 2, r = kr & 3;
    a_l[bb][i2][kr] = mod[b * 8192 + k * 2048 + r * 512 + ibase + i2]
                      * (s[b * 4 + k] * weff[r]);
  }
  // stage bp: 16b x 8kr x 32j (coalesced over j)
  {
    int kr = tid >> 5, k = kr >> 2, r = kr & 3;
    #pragma unroll
    for (int bb = 0; bb < 16; ++bb) {
      int b = bbase + bb;
      bp_l[bb][jl][kr] = mod[b * 8192 + k * 2048 + r * 512 + 256 + j]
                         * s[b * 4 + k];
    }
  }
  __syncthreads();

  #pragma unroll
  for (int bb = 0; bb < 16; ++bb) {
    const float* ap  = a_l[bb][il];
    const float* bpp = bp_l[bb][jl];
    float d0 = ap[0]*bpp[0] + ap[1]*bpp[1] + ap[2]*bpp[2] + ap[3]*bpp[3];
    float d1 = ap[4]*bpp[4] + ap[5]*bpp[5] + ap[6]*bpp[6] + ap[7]*bpp[7];
    float m0 = wm0 * (d0 + beff);
    float m1 = wm1 * (d1 + beff);
    float re = A1.x * m0 - A1.y * m1;
    float im = A1.x * m1 - A1.y * m0;
    float mg = sqrtf(re * re + im * im + 1e-4f);
    #pragma unroll
    for (int o = 1; o < 64; o <<= 1) mg += __shfl_xor(mg, o, 64);
    if ((tid & 63) == 0) atomicAdd(&bsum[bb], mg);
  }
  __syncthreads();
  if (tid < 16) atomicAdd(&partial[bbase + tid], bsum[tid]);
}

// ---------------------------------------------------------------------------
// K4 v3: same scheme as K2 v3 (grid (32,8,4), 16 b/block). ~46 independent
// global loads/thread up front (weights 12 floats -> regs; a/bp 40 floats ->
// LDS), ONE barrier, then 16 pure-LDS b-iterations each ending in a
// coalesced store. LDS bp stride 17 (coprime 32, conflict-free scalar).
// ---------------------------------------------------------------------------
__global__ __launch_bounds__(256) void k4_out(
    const float* __restrict__ mod, const float* __restrict__ s,
    const float* __restrict__ wstat,
    const float* __restrict__ wmod,
    const float* __restrict__ cw,
    const float* __restrict__ cb,
    const float* __restrict__ partial,
    float* __restrict__ out)
{
  const int ibase = blockIdx.x * 8, jbase = blockIdx.y * 32, bbase = blockIdx.z * 16;
  const int tid = threadIdx.x;
  const int il = tid >> 5, jl = tid & 31;
  const int i = ibase + il, j = jbase + jl;
  const int ij = i * 256 + j;

  __shared__ float a_l[16][8][16];    // 8 KB (broadcast reads)
  __shared__ float bp_l[16][32][17];  // 34 KB, stride 17 -> conflict-free
  __shared__ float inv_l[16];

  // weights for this thread's (i,j): independent loads, issue first
  const float wm0 = wmod[ij];
  const float wm1 = wmod[65536  + ij];
  const float wm2 = wmod[131072 + ij];
  const float wm3 = wmod[196608 + ij];
  const float2 A0 = *reinterpret_cast<const float2*>(wstat + ij * 2);
  const float2 A1 = *reinterpret_cast<const float2*>(wstat + 131072 + ij * 2);

  float weff[4]; float beff = 0.0f;
  #pragma unroll
  for (int r = 0; r < 4; ++r) {
    weff[r] = cw[r] + cw[4 + r] + cw[8 + r] + cw[12 + r];
    beff += cb[r];
  }
  if (tid < 16)
    inv_l[tid] = rsqrtf(partial[bbase + tid] * (1.0f / 65536.0f) + 1e-4f);

  // stage a: 16b x 8i x 16kr = 2048 (8 passes; s/partial L2-hot)
  #pragma unroll
  for (int q = 0; q < 8; ++q) {
    int ee = q * 256 + tid;
    int bb = ee >> 7, kr = (ee >> 3) & 15, i2 = ee & 7;
    int b = bbase + bb, k = kr >> 2, r = kr & 3;
    a_l[bb][i2][kr] = mod[b * 8192 + k * 2048 + r * 512 + ibase + i2]
                      * (s[b * 4 + k] * weff[r]);
  }
  // stage bp: 16b x 16kr x 32j (coalesced over j)
  {
    int kr0 = tid >> 5;
    #pragma unroll
    for (int bb = 0; bb < 16; ++bb) {
      int b = bbase + bb;
      #pragma unroll
      for (int h = 0; h < 2; ++h) {
        int kr = kr0 + h * 8, k = kr >> 2, r = kr & 3;
        bp_l[bb][jl][kr] = mod[b * 8192 + k * 2048 + r * 512 + 256 + j]
                           * s[b * 4 + k];
      }
    }
  }
  __syncthreads();

  #pragma unroll
  for (int bb = 0; bb < 16; ++bb) {
    const int b = bbase + bb;
    const float* ap  = a_l[bb][il];
    const float* bpp = bp_l[bb][jl];
    float d0 = ap[0]*bpp[0] + ap[1]*bpp[1] + ap[2]*bpp[2] + ap[3]*bpp[3];
    float d1 = ap[4]*bpp[4] + ap[5]*bpp[5] + ap[6]*bpp[6] + ap[7]*bpp[7];
    float d2 = ap[8]*bpp[8] + ap[9]*bpp[9] + ap[10]*bpp[10] + ap[11]*bpp[11];
    float d3 = ap[12]*bpp[12] + ap[13]*bpp[13] + ap[14]*bpp[14] + ap[15]*bpp[15];
    float m0 = wm0 * (d0 + beff);
    float m1 = wm1 * (d1 + beff);
    float m2 = wm2 * (d2 + beff);
    float m3 = wm3 * (d3 + beff);
    float re = A1.x * m0 - A1.y * m1;
    float im = A1.x * m1 - A1.y * m0;
    float inv = inv_l[bb];
    float mwre = A0.x + re * inv;
    float mwim = A0.y + im * inv;
    float rd = rsqrtf(m2 * m2 + m3 * m3 + 1e-4f);
    out[b * 65536 + ij] = (mwre * m2 + mwim * m3) * rd;
  }
}

extern "C" void kernel_launch(void* const* d_in, const int* in_sizes, int n_in,
                              void* d_out, int out_size, void* d_ws, size_t ws_size,
                              hipStream_t stream) {
  const float* x     = (const float*)d_in[0];
  const float* Wt    = (const float*)d_in[1];
  const float* Wg    = (const float*)d_in[2];
  const float* wstat = (const float*)d_in[3];
  const float* wmod  = (const float*)d_in[4];
  const float* cw    = (const float*)d_in[5];
  const float* cb    = (const float*)d_in[6];

  float* mod     = (float*)d_ws;           // 524288 floats
  float* sbuf    = mod + 524288;           // 256 floats (rsqrt scales)
  float* partial = sbuf + 256;             // 64 floats (per-b mag sums)

  hipMemsetAsync(partial, 0, 64 * sizeof(float), stream);
  k1_gemm  <<<512, 256, 0, stream>>>(x, Wt, Wg, mod);
  k1b_scale<<<256, 256, 0, stream>>>(mod, sbuf);
  k2_mag   <<<dim3(32, 8, 4), 256, 0, stream>>>(mod, sbuf, wstat, wmod, cw, cb, partial);
  k4_out   <<<dim3(32, 8, 4), 256, 0, stream>>>(mod, sbuf, wstat, wmod, cw, cb, partial,
                                                (float*)d_out);
}